// Round 1
// baseline (812.022 us; speedup 1.0000x reference)
//
#include <hip/hip_runtime.h>
#include <math.h>

#define SLOPE_ 0.2f
constexpr int kB = 64, kT = 512, kD = 8, kL = 2, kH = 128, kE = 96;
constexpr int kFG = 145;            // H + L*D + 1
constexpr int kTM = 510;            // T - L
constexpr int kN = kB * kTM;        // 32640
constexpr int TILE = 32;
constexpr int WPAD = 132;           // 128 + 4 pad: conflict-free b128 reads

// ---- 4x4 microtile accumulate over a 32-wide k chunk -----------------------
// shw is transposed [k][h]; shh/sht are [n][128] activations (primal/tangent).
template<bool TAN>
__device__ __forceinline__ void gemm_chunk(
    const float (*shw)[WPAD], const float (*shh)[kH], const float (*sht)[kH],
    int kc, int n0, int h0, float acc[4][4], float tacc[4][4])
{
  #pragma unroll
  for (int kk = 0; kk < 32; kk += 4) {
    float wr[4][4];
    *(float4*)&wr[0][0] = *(const float4*)&shw[kk+0][h0];
    *(float4*)&wr[1][0] = *(const float4*)&shw[kk+1][h0];
    *(float4*)&wr[2][0] = *(const float4*)&shw[kk+2][h0];
    *(float4*)&wr[3][0] = *(const float4*)&shw[kk+3][h0];
    #pragma unroll
    for (int i = 0; i < 4; ++i) {
      float4 a4 = *(const float4*)&shh[n0+i][kc+kk];
      float av[4] = {a4.x, a4.y, a4.z, a4.w};
      #pragma unroll
      for (int kq = 0; kq < 4; ++kq)
        #pragma unroll
        for (int j = 0; j < 4; ++j)
          acc[i][j] = fmaf(av[kq], wr[kq][j], acc[i][j]);
      if (TAN) {
        float4 t4 = *(const float4*)&sht[n0+i][kc+kk];
        float tv[4] = {t4.x, t4.y, t4.z, t4.w};
        #pragma unroll
        for (int kq = 0; kq < 4; ++kq)
          #pragma unroll
          for (int j = 0; j < 4; ++j)
            tacc[i][j] = fmaf(tv[kq], wr[kq][j], tacc[i][j]);
      }
    }
  }
}

// stage a 32-wide k chunk of W (row stride `stride` floats, 16B-aligned rows)
// transposed into shw[k][h]; 128 rows.
__device__ __forceinline__ void load_w_aligned(
    float (*shw)[WPAD], const float* __restrict__ W, int stride, int kc, int tid)
{
  #pragma unroll
  for (int i = 0; i < 4; ++i) {
    int idx = tid + i*256;           // 1024 float4s total
    int h = idx >> 3, c4 = idx & 7;
    float4 v = *(const float4*)(W + h*stride + kc + c4*4);
    shw[c4*4+0][h] = v.x;
    shw[c4*4+1][h] = v.y;
    shw[c4*4+2][h] = v.z;
    shw[c4*4+3][h] = v.w;
  }
}

// ---- fc_mlp: emb (N,96) -> emb_h (N,128) -----------------------------------
__global__ __launch_bounds__(256) void fc_kernel(
    const float* __restrict__ emb,
    const float* __restrict__ W0, const float* __restrict__ b0,
    const float* __restrict__ W1, const float* __restrict__ b1,
    const float* __restrict__ Wf, const float* __restrict__ bf,
    float* __restrict__ out)
{
  __shared__ float shh[TILE][kH];
  __shared__ float shw[32][WPAD];
  const int tid = threadIdx.x;
  const int hg = tid & 31, ng = tid >> 5;
  const int h0 = hg*4, n0 = ng*4;
  const int bn = blockIdx.x * TILE;

  // load emb tile (32 x 96), row stride kH in LDS
  #pragma unroll
  for (int i = 0; i < 3; ++i) {
    int idx = tid + i*256;           // 768 float4s
    int r = idx / 24, c4 = idx % 24;
    *(float4*)&shh[r][c4*4] = *(const float4*)(emb + (bn + r)*kE + c4*4);
  }

  float acc[4][4];

  // layer 0 (k = 96)
  #pragma unroll
  for (int i = 0; i < 4; ++i)
    #pragma unroll
    for (int j = 0; j < 4; ++j) acc[i][j] = 0.f;
  for (int kc = 0; kc < kE; kc += 32) {
    __syncthreads();
    load_w_aligned(shw, W0, kE, kc, tid);
    __syncthreads();
    gemm_chunk<false>(shw, shh, shh, kc, n0, h0, acc, acc);
  }
  __syncthreads();
  #pragma unroll
  for (int i = 0; i < 4; ++i)
    #pragma unroll
    for (int j = 0; j < 4; ++j) {
      float z = acc[i][j] + b0[h0+j];
      shh[n0+i][h0+j] = z >= 0.f ? z : SLOPE_*z;
    }

  // layer 1 (k = 128)
  #pragma unroll
  for (int i = 0; i < 4; ++i)
    #pragma unroll
    for (int j = 0; j < 4; ++j) acc[i][j] = 0.f;
  for (int kc = 0; kc < kH; kc += 32) {
    __syncthreads();
    load_w_aligned(shw, W1, kH, kc, tid);
    __syncthreads();
    gemm_chunk<false>(shw, shh, shh, kc, n0, h0, acc, acc);
  }
  __syncthreads();
  #pragma unroll
  for (int i = 0; i < 4; ++i)
    #pragma unroll
    for (int j = 0; j < 4; ++j) {
      float z = acc[i][j] + b1[h0+j];
      shh[n0+i][h0+j] = z >= 0.f ? z : SLOPE_*z;
    }

  // final (k = 128, no activation) -> global
  #pragma unroll
  for (int i = 0; i < 4; ++i)
    #pragma unroll
    for (int j = 0; j < 4; ++j) acc[i][j] = 0.f;
  for (int kc = 0; kc < kH; kc += 32) {
    __syncthreads();
    load_w_aligned(shw, Wf, kH, kc, tid);
    __syncthreads();
    gemm_chunk<false>(shw, shh, shh, kc, n0, h0, acc, acc);
  }
  #pragma unroll
  for (int i = 0; i < 4; ++i) {
    float4 o;
    o.x = acc[i][0] + bf[h0+0];
    o.y = acc[i][1] + bf[h0+1];
    o.z = acc[i][2] + bf[h0+2];
    o.w = acc[i][3] + bf[h0+3];
    *(float4*)(out + (bn + n0 + i)*kH + h0) = o;
  }
}

// ---- g_mlp forward + JVP (tangent = e_{144}) -------------------------------
__global__ __launch_bounds__(256) void g_kernel(
    const float* __restrict__ x,
    const float* __restrict__ embh,
    const float* __restrict__ gW0, const float* __restrict__ gb0,
    const float* __restrict__ gW1, const float* __restrict__ gb1,
    const float* __restrict__ gW2, const float* __restrict__ gb2,
    const float* __restrict__ gWf, const float* __restrict__ gbf,
    float* __restrict__ resid, float* __restrict__ logterm)
{
  const int d  = blockIdx.y;
  const int bn = blockIdx.x * TILE;
  __shared__ float shh[TILE][kH];
  __shared__ float sht[TILE][kH];
  __shared__ float shw[32][WPAD];
  __shared__ float shyy[TILE][16];
  __shared__ float shx[TILE];
  const int tid = threadIdx.x;
  const int hg = tid & 31, ng = tid >> 5;
  const int h0 = hg*4, n0 = ng*4;

  // stage emb_h tile (32 x 128)
  #pragma unroll
  for (int i = 0; i < 4; ++i) {
    int idx = tid + i*256;
    int r = idx >> 5, c4 = idx & 31;
    *(float4*)&shh[r][c4*4] = *(const float4*)(embh + (bn + r)*kH + c4*4);
  }
  // stage yy (32 x 16): yy[n][l*8+dd] = x[b, t+l, dd]
  {
    int r = tid >> 3, c2 = tid & 7;
    int n = bn + r; int b = n / kTM; int t = n - b*kTM;
    int col = c2*2; int l = col >> 3; int dd = col & 7;
    float2 v = *(const float2*)(x + ((b*kT + t + l)*kD + dd));
    shyy[r][col]   = v.x;
    shyy[r][col+1] = v.y;
  }
  // stage xx (32): x[b, t+L, d]
  if (tid < TILE) {
    int n = bn + tid; int b = n / kTM; int t = n - b*kTM;
    shx[tid] = x[(b*kT + t + kL)*kD + d];
  }

  const float* W0d = gW0 + d*kH*kFG;
  float acc[4][4], tacc[4][4];
  #pragma unroll
  for (int i = 0; i < 4; ++i)
    #pragma unroll
    for (int j = 0; j < 4; ++j) { acc[i][j] = 0.f; tacc[i][j] = 0.f; }

  // ---- layer 0: emb part (k = 0..127); gW0 rows are 145 floats (misaligned)
  for (int kc = 0; kc < kH; kc += 32) {
    __syncthreads();
    #pragma unroll
    for (int i = 0; i < 16; ++i) {
      int idx = tid + i*256;
      int h = idx >> 5, c = idx & 31;
      shw[c][h] = W0d[h*kFG + kc + c];
    }
    __syncthreads();
    gemm_chunk<false>(shw, shh, sht, kc, n0, h0, acc, tacc);
  }
  // ---- layer 0: yy part (k = 128..143)
  __syncthreads();
  #pragma unroll
  for (int i = 0; i < 8; ++i) {
    int idx = tid + i*256;
    int h = idx >> 4, c = idx & 15;
    shw[c][h] = W0d[h*kFG + 128 + c];
  }
  __syncthreads();
  #pragma unroll
  for (int kk = 0; kk < 16; kk += 4) {
    float wr[4][4];
    *(float4*)&wr[0][0] = *(const float4*)&shw[kk+0][h0];
    *(float4*)&wr[1][0] = *(const float4*)&shw[kk+1][h0];
    *(float4*)&wr[2][0] = *(const float4*)&shw[kk+2][h0];
    *(float4*)&wr[3][0] = *(const float4*)&shw[kk+3][h0];
    #pragma unroll
    for (int i = 0; i < 4; ++i) {
      float4 a4 = *(const float4*)&shyy[n0+i][kk];
      float av[4] = {a4.x, a4.y, a4.z, a4.w};
      #pragma unroll
      for (int kq = 0; kq < 4; ++kq)
        #pragma unroll
        for (int j = 0; j < 4; ++j)
          acc[i][j] = fmaf(av[kq], wr[kq][j], acc[i][j]);
    }
  }
  // ---- layer 0: x term, bias, activation; tangent dz0[h] = W0[h][144]
  float w144[4];
  #pragma unroll
  for (int j = 0; j < 4; ++j) w144[j] = W0d[(h0+j)*kFG + 144];
  __syncthreads();   // all reads of shh (emb) complete before overwrite
  #pragma unroll
  for (int i = 0; i < 4; ++i) {
    float xi = shx[n0+i];
    #pragma unroll
    for (int j = 0; j < 4; ++j) {
      float z = acc[i][j] + xi*w144[j] + gb0[d*kH + h0 + j];
      float m = z >= 0.f ? 1.f : SLOPE_;
      shh[n0+i][h0+j] = z*m;
      sht[n0+i][h0+j] = w144[j]*m;
    }
  }

  // ---- layers 1 and 2 (k = 128), primal + tangent share weight loads
  const float* Wl[2] = { gW1 + d*kH*kH, gW2 + d*kH*kH };
  const float* bl[2] = { gb1 + d*kH,    gb2 + d*kH };
  for (int layer = 0; layer < 2; ++layer) {
    #pragma unroll
    for (int i = 0; i < 4; ++i)
      #pragma unroll
      for (int j = 0; j < 4; ++j) { acc[i][j] = 0.f; tacc[i][j] = 0.f; }
    for (int kc = 0; kc < kH; kc += 32) {
      __syncthreads();
      load_w_aligned(shw, Wl[layer], kH, kc, tid);
      __syncthreads();
      gemm_chunk<true>(shw, shh, sht, kc, n0, h0, acc, tacc);
    }
    __syncthreads();
    #pragma unroll
    for (int i = 0; i < 4; ++i)
      #pragma unroll
      for (int j = 0; j < 4; ++j) {
        float z = acc[i][j] + bl[layer][h0+j];
        float m = z >= 0.f ? 1.f : SLOPE_;
        shh[n0+i][h0+j] = z*m;
        sht[n0+i][h0+j] = tacc[i][j]*m;
      }
  }

  // ---- final layer: dot with gWf[d] (128), 8 threads per row
  __syncthreads();
  {
    int r = tid >> 3, g = tid & 7;
    const float* wf = gWf + d*kH;
    float p = 0.f, tp = 0.f;
    #pragma unroll
    for (int q = 0; q < 4; ++q) {
      int k = g*16 + q*4;
      float4 w4 = *(const float4*)(wf + k);
      float4 h4 = *(const float4*)&shh[r][k];
      float4 t4 = *(const float4*)&sht[r][k];
      p  += h4.x*w4.x + h4.y*w4.y + h4.z*w4.z + h4.w*w4.w;
      tp += t4.x*w4.x + t4.y*w4.y + t4.z*w4.z + t4.w*w4.w;
    }
    #pragma unroll
    for (int s = 4; s > 0; s >>= 1) {
      p  += __shfl_down(p, s, 8);
      tp += __shfl_down(tp, s, 8);
    }
    if (g == 0) {
      int n = bn + r;
      resid[n*kD + d]   = p + gbf[d];
      logterm[n*kD + d] = logf(fabsf(tp));
    }
  }
}

// ---- per-batch sum of 510*8 log terms --------------------------------------
__global__ __launch_bounds__(256) void reduce_kernel(
    const float* __restrict__ lt, float* __restrict__ out)
{
  const int b = blockIdx.x;
  float s = 0.f;
  for (int i = threadIdx.x; i < kTM*kD; i += 256)
    s += lt[b*kTM*kD + i];
  #pragma unroll
  for (int off = 32; off > 0; off >>= 1) s += __shfl_down(s, off, 64);
  __shared__ float red[4];
  if ((threadIdx.x & 63) == 0) red[threadIdx.x >> 6] = s;
  __syncthreads();
  if (threadIdx.x == 0) out[b] = red[0] + red[1] + red[2] + red[3];
}

extern "C" void kernel_launch(void* const* d_in, const int* in_sizes, int n_in,
                              void* d_out, int out_size, void* d_ws, size_t ws_size,
                              hipStream_t stream) {
  const float* x    = (const float*)d_in[0];
  const float* emb  = (const float*)d_in[1];
  const float* fcW0 = (const float*)d_in[2];
  const float* fcb0 = (const float*)d_in[3];
  const float* fcW1 = (const float*)d_in[4];
  const float* fcb1 = (const float*)d_in[5];
  const float* fcWf = (const float*)d_in[6];
  const float* fcbf = (const float*)d_in[7];
  const float* gW0  = (const float*)d_in[8];
  const float* gb0  = (const float*)d_in[9];
  const float* gW1  = (const float*)d_in[10];
  const float* gb1  = (const float*)d_in[11];
  const float* gW2  = (const float*)d_in[12];
  const float* gb2  = (const float*)d_in[13];
  const float* gWf  = (const float*)d_in[14];
  const float* gbf  = (const float*)d_in[15];
  float* out = (float*)d_out;

  float* embh    = (float*)d_ws;             // N * 128
  float* logterm = embh + (size_t)kN * kH;   // N * 8

  fc_kernel<<<kN / TILE, 256, 0, stream>>>(emb, fcW0, fcb0, fcW1, fcb1,
                                           fcWf, fcbf, embh);
  g_kernel<<<dim3(kN / TILE, kD), 256, 0, stream>>>(
      x, embh, gW0, gb0, gW1, gb1, gW2, gb2, gWf, gbf, out, logterm);
  reduce_kernel<<<kB, 256, 0, stream>>>(logterm, out + (size_t)kN * kD);
}

// Round 2
// 236.326 us; speedup vs baseline: 3.4360x; 3.4360x over previous
//
#include <hip/hip_runtime.h>
#include <math.h>

typedef _Float16 f16;
typedef _Float16 f16x4 __attribute__((ext_vector_type(4)));
typedef _Float16 f16x8 __attribute__((ext_vector_type(8)));
typedef float f32x16 __attribute__((ext_vector_type(16)));

#define MFMA_ __builtin_amdgcn_mfma_f32_32x32x16_f16
#define SLOPE_ 0.2f
constexpr int kB = 64, kT = 512, kD = 8, kL = 2, kH = 128, kE = 96;
constexpr int kFG = 145;            // H + L*D + 1
constexpr int kTM = 510;            // T - L
constexpr int kN = kB * kTM;        // 32640
constexpr int kK0 = 160;            // L0 K padded (145 -> 160)

// LDS strides (f16 elems). All chosen 16B-multiple row pitch, gcd(words,32)=4
constexpr int SA  = 136;            // activations, K=128
constexpr int S0  = 168;            // A0, K=160
constexpr int SW0 = 88;             // W0 half-stage, 80 k
constexpr int SW  = 72;             // W1/W2 half-stage, 64 k

// ============================ fp32 tile GEMM (fc) ===========================
constexpr int TILE = 32;
constexpr int WPAD = 132;

__device__ __forceinline__ void gemm_chunk(
    const float (*shw)[WPAD], const float (*shh)[kH],
    int kc, int n0, int h0, float acc[4][4])
{
  #pragma unroll
  for (int kk = 0; kk < 32; kk += 4) {
    float wr[4][4];
    *(float4*)&wr[0][0] = *(const float4*)&shw[kk+0][h0];
    *(float4*)&wr[1][0] = *(const float4*)&shw[kk+1][h0];
    *(float4*)&wr[2][0] = *(const float4*)&shw[kk+2][h0];
    *(float4*)&wr[3][0] = *(const float4*)&shw[kk+3][h0];
    #pragma unroll
    for (int i = 0; i < 4; ++i) {
      float4 a4 = *(const float4*)&shh[n0+i][kc+kk];
      float av[4] = {a4.x, a4.y, a4.z, a4.w};
      #pragma unroll
      for (int kq = 0; kq < 4; ++kq)
        #pragma unroll
        for (int j = 0; j < 4; ++j)
          acc[i][j] = fmaf(av[kq], wr[kq][j], acc[i][j]);
    }
  }
}

__device__ __forceinline__ void load_w_aligned(
    float (*shw)[WPAD], const float* __restrict__ W, int stride, int kc, int tid)
{
  #pragma unroll
  for (int i = 0; i < 4; ++i) {
    int idx = tid + i*256;
    int h = idx >> 3, c4 = idx & 7;
    float4 v = *(const float4*)(W + h*stride + kc + c4*4);
    shw[c4*4+0][h] = v.x;
    shw[c4*4+1][h] = v.y;
    shw[c4*4+2][h] = v.z;
    shw[c4*4+3][h] = v.w;
  }
}

// fc_mlp: emb (N,96) -> emb_h (N,128) fp16
__global__ __launch_bounds__(256) void fc_kernel(
    const float* __restrict__ emb,
    const float* __restrict__ W0, const float* __restrict__ b0,
    const float* __restrict__ W1, const float* __restrict__ b1,
    const float* __restrict__ Wf, const float* __restrict__ bf,
    f16* __restrict__ out)
{
  __shared__ float shh[TILE][kH];
  __shared__ float shw[32][WPAD];
  const int tid = threadIdx.x;
  const int hg = tid & 31, ng = tid >> 5;
  const int h0 = hg*4, n0 = ng*4;
  const int bn = blockIdx.x * TILE;

  #pragma unroll
  for (int i = 0; i < 3; ++i) {
    int idx = tid + i*256;
    int r = idx / 24, c4 = idx % 24;
    *(float4*)&shh[r][c4*4] = *(const float4*)(emb + (bn + r)*kE + c4*4);
  }

  float acc[4][4];
  // layer 0 (k=96)
  #pragma unroll
  for (int i = 0; i < 4; ++i)
    #pragma unroll
    for (int j = 0; j < 4; ++j) acc[i][j] = 0.f;
  for (int kc = 0; kc < kE; kc += 32) {
    __syncthreads();
    load_w_aligned(shw, W0, kE, kc, tid);
    __syncthreads();
    gemm_chunk(shw, shh, kc, n0, h0, acc);
  }
  __syncthreads();
  #pragma unroll
  for (int i = 0; i < 4; ++i)
    #pragma unroll
    for (int j = 0; j < 4; ++j) {
      float z = acc[i][j] + b0[h0+j];
      shh[n0+i][h0+j] = z >= 0.f ? z : SLOPE_*z;
    }
  // layer 1
  #pragma unroll
  for (int i = 0; i < 4; ++i)
    #pragma unroll
    for (int j = 0; j < 4; ++j) acc[i][j] = 0.f;
  for (int kc = 0; kc < kH; kc += 32) {
    __syncthreads();
    load_w_aligned(shw, W1, kH, kc, tid);
    __syncthreads();
    gemm_chunk(shw, shh, kc, n0, h0, acc);
  }
  __syncthreads();
  #pragma unroll
  for (int i = 0; i < 4; ++i)
    #pragma unroll
    for (int j = 0; j < 4; ++j) {
      float z = acc[i][j] + b1[h0+j];
      shh[n0+i][h0+j] = z >= 0.f ? z : SLOPE_*z;
    }
  // final
  #pragma unroll
  for (int i = 0; i < 4; ++i)
    #pragma unroll
    for (int j = 0; j < 4; ++j) acc[i][j] = 0.f;
  for (int kc = 0; kc < kH; kc += 32) {
    __syncthreads();
    load_w_aligned(shw, Wf, kH, kc, tid);
    __syncthreads();
    gemm_chunk(shw, shh, kc, n0, h0, acc);
  }
  #pragma unroll
  for (int i = 0; i < 4; ++i) {
    f16x4 o;
    o[0] = (f16)(acc[i][0] + bf[h0+0]);
    o[1] = (f16)(acc[i][1] + bf[h0+1]);
    o[2] = (f16)(acc[i][2] + bf[h0+2]);
    o[3] = (f16)(acc[i][3] + bf[h0+3]);
    *(f16x4*)(out + (size_t)(bn + n0 + i)*kH + h0) = o;
  }
}

// ================== weight pre-convert: f32 -> f16 images ===================
__global__ __launch_bounds__(256) void cvt_kernel(
    const float* __restrict__ gW0, const float* __restrict__ gW1,
    const float* __restrict__ gW2,
    f16* __restrict__ W0img, f16* __restrict__ W1img, f16* __restrict__ W2img)
{
  const int stride = gridDim.x * 256;
  for (int idx = blockIdx.x*256 + threadIdx.x; idx < kD*kH*kK0; idx += stride) {
    int dcol = idx / kK0, k = idx - dcol*kK0;
    W0img[idx] = (f16)(k < kFG ? gW0[dcol*kFG + k] : 0.f);
  }
  for (int idx = blockIdx.x*256 + threadIdx.x; idx < kD*kH*kH; idx += stride) {
    W1img[idx] = (f16)gW1[idx];
    W2img[idx] = (f16)gW2[idx];
  }
}

// ==================== g_mlp fwd + JVP, fp16 MFMA ============================
// Block: one d, 64 primal rows. 4 waves: wave -> (rowtile = wave&1,
// colhalf = wave>>1). Each wave: 32 primal + 32 tangent rows x 64 cols.
__global__ __launch_bounds__(256, 3) void g_kernel(
    const float* __restrict__ x, const f16* __restrict__ embh,
    const f16* __restrict__ W0img, const f16* __restrict__ W1img,
    const f16* __restrict__ W2img,
    const float* __restrict__ gb0, const float* __restrict__ gb1,
    const float* __restrict__ gb2, const float* __restrict__ gWf,
    const float* __restrict__ gbf,
    float* __restrict__ resid, float* __restrict__ logterm)
{
  __shared__ char smem[53760];
  f16 (*actH)[SA] = (f16(*)[SA])(smem);            // 64 x 136   (17408 B)
  f16 (*actT)[SA] = (f16(*)[SA])(smem + 17408);    // 64 x 136   (17408 B)
  f16 (*wbuf)[SW] = (f16(*)[SW])(smem + 34816);    // 128 x 72   (18432 B)
  f16 (*A0)[S0]   = (f16(*)[S0])(smem);            // 64 x 168   (L0 phase)
  f16 (*W0b)[SW0] = (f16(*)[SW0])(smem + 21504);   // 128 x 88   (L0 phase)
  float* swf      = (float*)(smem + 53248);        // 128 f32

  const int d   = blockIdx.y;
  const int bn  = blockIdx.x * 64;
  const int tid = threadIdx.x;
  const int wave = tid >> 6, lane = tid & 63;
  const int l31 = lane & 31;
  const int lh8 = (lane >> 5) * 8;    // k-offset of this half-wave's fragment
  const int lr4 = (lane >> 5) * 4;    // C/D row offset
  const int rowti = (wave & 1) * 32;
  const int colh  = (wave >> 1) * 64;

  if (tid < kH) swf[tid] = gWf[d*kH + tid];

  // ---- stage A0 = [embh | yy | xx_d | 0pad], 64 x 160
  #pragma unroll
  for (int i = 0; i < 4; ++i) {
    int idx = tid + i*256; int r = idx >> 4, c8 = idx & 15;
    *(f16x8*)&A0[r][c8*8] = *(const f16x8*)(embh + (size_t)(bn + r)*kH + c8*8);
  }
  #pragma unroll
  for (int i = 0; i < 8; ++i) {
    int idx = tid + i*256; int r = idx >> 5, c = idx & 31;  // col = 128+c
    int n = bn + r, b = n / kTM, t = n - b*kTM;
    float v;
    if (c < 16)       v = x[(b*kT + t + (c >> 3))*kD + (c & 7)];
    else if (c == 16) v = x[(b*kT + t + kL)*kD + d];
    else              v = 0.f;
    A0[r][128 + c] = (f16)v;
  }
  // stage W0 half0 (k 0..79)
  const f16* W0d = W0img + d*kH*kK0;
  #pragma unroll
  for (int i = 0; i < 5; ++i) {
    int idx = tid + i*256; int col = idx / 10, c8 = idx - col*10;
    *(f16x8*)&W0b[col][c8*8] = *(const f16x8*)(W0d + col*kK0 + c8*8);
  }
  __syncthreads();

  // ---- L0 MFMA (primal only; tangent L0 is W0[:,144]*mask, free)
  f32x16 p0 = {}, p1 = {};
  #pragma unroll
  for (int kk = 0; kk < 5; ++kk) {
    f16x8 a  = *(const f16x8*)&A0[rowti + l31][kk*16 + lh8];
    f16x8 b0 = *(const f16x8*)&W0b[colh + l31][kk*16 + lh8];
    f16x8 b1 = *(const f16x8*)&W0b[colh + 32 + l31][kk*16 + lh8];
    p0 = MFMA_(a, b0, p0, 0, 0, 0);
    p1 = MFMA_(a, b1, p1, 0, 0, 0);
  }
  __syncthreads();
  // stage W0 half1 (k 80..159)
  #pragma unroll
  for (int i = 0; i < 5; ++i) {
    int idx = tid + i*256; int col = idx / 10, c8 = idx - col*10;
    *(f16x8*)&W0b[col][c8*8] = *(const f16x8*)(W0d + col*kK0 + 80 + c8*8);
  }
  __syncthreads();
  #pragma unroll
  for (int kk = 0; kk < 5; ++kk) {
    f16x8 a  = *(const f16x8*)&A0[rowti + l31][80 + kk*16 + lh8];
    f16x8 b0 = *(const f16x8*)&W0b[colh + l31][kk*16 + lh8];
    f16x8 b1 = *(const f16x8*)&W0b[colh + 32 + l31][kk*16 + lh8];
    p0 = MFMA_(a, b0, p0, 0, 0, 0);
    p1 = MFMA_(a, b1, p1, 0, 0, 0);
  }
  // w144 (local k = 144-80 = 64) and bias, read before act buffers overwrite
  float w144_0 = (float)W0b[colh + l31][64];
  float w144_1 = (float)W0b[colh + 32 + l31][64];
  float bb0 = gb0[d*kH + colh + l31];
  float bb1 = gb0[d*kH + colh + 32 + l31];
  __syncthreads();
  // ---- L0 epilogue: H0 = lrelu(z), T0 = w144 * mask
  #pragma unroll
  for (int r = 0; r < 16; ++r) {
    int row = rowti + (r & 3) + ((r >> 2) * 8) + lr4;
    float z0 = p0[r] + bb0; float m0 = z0 >= 0.f ? 1.f : SLOPE_;
    actH[row][colh + l31] = (f16)(z0*m0);
    actT[row][colh + l31] = (f16)(w144_0*m0);
    float z1 = p1[r] + bb1; float m1 = z1 >= 0.f ? 1.f : SLOPE_;
    actH[row][colh + 32 + l31] = (f16)(z1*m1);
    actT[row][colh + 32 + l31] = (f16)(w144_1*m1);
  }
  __syncthreads();

  // ---- layers 1 & 2: primal + tangent share weight fragments
  const f16*  Wimg[2] = { W1img + d*kH*kH, W2img + d*kH*kH };
  const float* gbl[2] = { gb1 + d*kH,      gb2 + d*kH };
  #pragma unroll 1
  for (int layer = 0; layer < 2; ++layer) {
    f32x16 pa0 = {}, pa1 = {}, ta0 = {}, ta1 = {};
    const f16* W = Wimg[layer];
    #pragma unroll
    for (int half = 0; half < 2; ++half) {
      #pragma unroll
      for (int i = 0; i < 4; ++i) {
        int idx = tid + i*256; int col = idx >> 3, c8 = idx & 7;
        *(f16x8*)&wbuf[col][c8*8] =
            *(const f16x8*)(W + col*kH + half*64 + c8*8);
      }
      __syncthreads();
      #pragma unroll
      for (int kk = 0; kk < 4; ++kk) {
        int ko = half*64 + kk*16 + lh8;
        f16x8 aP = *(const f16x8*)&actH[rowti + l31][ko];
        f16x8 aT = *(const f16x8*)&actT[rowti + l31][ko];
        f16x8 b0 = *(const f16x8*)&wbuf[colh + l31][kk*16 + lh8];
        f16x8 b1 = *(const f16x8*)&wbuf[colh + 32 + l31][kk*16 + lh8];
        pa0 = MFMA_(aP, b0, pa0, 0, 0, 0);
        pa1 = MFMA_(aP, b1, pa1, 0, 0, 0);
        ta0 = MFMA_(aT, b0, ta0, 0, 0, 0);
        ta1 = MFMA_(aT, b1, ta1, 0, 0, 0);
      }
      __syncthreads();
    }
    float bc0 = gbl[layer][colh + l31];
    float bc1 = gbl[layer][colh + 32 + l31];
    #pragma unroll
    for (int r = 0; r < 16; ++r) {
      int row = rowti + (r & 3) + ((r >> 2) * 8) + lr4;
      float z0 = pa0[r] + bc0; float m0 = z0 >= 0.f ? 1.f : SLOPE_;
      actH[row][colh + l31] = (f16)(z0*m0);
      actT[row][colh + l31] = (f16)(ta0[r]*m0);
      float z1 = pa1[r] + bc1; float m1 = z1 >= 0.f ? 1.f : SLOPE_;
      actH[row][colh + 32 + l31] = (f16)(z1*m1);
      actT[row][colh + 32 + l31] = (f16)(ta1[r]*m1);
    }
    __syncthreads();
  }

  // ---- final: p = H2 . wf, tp = T2 . wf  (4 threads per row)
  {
    int r = tid >> 2, q = (tid & 3) * 32;
    float p = 0.f, tp = 0.f;
    #pragma unroll
    for (int j = 0; j < 32; j += 8) {
      f16x8 h8 = *(const f16x8*)&actH[r][q + j];
      f16x8 t8 = *(const f16x8*)&actT[r][q + j];
      #pragma unroll
      for (int e = 0; e < 8; ++e) {
        float w = swf[q + j + e];
        p  += (float)h8[e] * w;
        tp += (float)t8[e] * w;
      }
    }
    p  += __shfl_down(p, 2, 4);  p  += __shfl_down(p, 1, 4);
    tp += __shfl_down(tp, 2, 4); tp += __shfl_down(tp, 1, 4);
    if ((tid & 3) == 0) {
      int n = bn + r;
      resid[(size_t)n*kD + d]   = p + gbf[d];
      logterm[(size_t)n*kD + d] = logf(fabsf(tp));
    }
  }
}

// ---- per-batch sum of 510*8 log terms --------------------------------------
__global__ __launch_bounds__(256) void reduce_kernel(
    const float* __restrict__ lt, float* __restrict__ out)
{
  const int b = blockIdx.x;
  float s = 0.f;
  for (int i = threadIdx.x; i < kTM*kD; i += 256)
    s += lt[b*kTM*kD + i];
  #pragma unroll
  for (int off = 32; off > 0; off >>= 1) s += __shfl_down(s, off, 64);
  __shared__ float red[4];
  if ((threadIdx.x & 63) == 0) red[threadIdx.x >> 6] = s;
  __syncthreads();
  if (threadIdx.x == 0) out[b] = red[0] + red[1] + red[2] + red[3];
}

extern "C" void kernel_launch(void* const* d_in, const int* in_sizes, int n_in,
                              void* d_out, int out_size, void* d_ws, size_t ws_size,
                              hipStream_t stream) {
  const float* x    = (const float*)d_in[0];
  const float* emb  = (const float*)d_in[1];
  const float* fcW0 = (const float*)d_in[2];
  const float* fcb0 = (const float*)d_in[3];
  const float* fcW1 = (const float*)d_in[4];
  const float* fcb1 = (const float*)d_in[5];
  const float* fcWf = (const float*)d_in[6];
  const float* fcbf = (const float*)d_in[7];
  const float* gW0  = (const float*)d_in[8];
  const float* gb0  = (const float*)d_in[9];
  const float* gW1  = (const float*)d_in[10];
  const float* gb1  = (const float*)d_in[11];
  const float* gW2  = (const float*)d_in[12];
  const float* gb2  = (const float*)d_in[13];
  const float* gWf  = (const float*)d_in[14];
  const float* gbf  = (const float*)d_in[15];
  float* out = (float*)d_out;

  // workspace layout
  f16*   embh    = (f16*)d_ws;                                    // N*128 f16
  float* logterm = (float*)((char*)d_ws + (size_t)kN*kH*2);       // N*8 f32
  f16*   W0img   = (f16*)((char*)logterm + (size_t)kN*kD*4);      // 8*128*160
  f16*   W1img   = W0img + kD*kH*kK0;                             // 8*128*128
  f16*   W2img   = W1img + kD*kH*kH;                              // 8*128*128

  cvt_kernel<<<256, 256, 0, stream>>>(gW0, gW1, gW2, W0img, W1img, W2img);
  fc_kernel<<<kN / TILE, 256, 0, stream>>>(emb, fcW0, fcb0, fcW1, fcb1,
                                           fcWf, fcbf, embh);
  g_kernel<<<dim3(kN / 64, kD), 256, 0, stream>>>(
      x, embh, W0img, W1img, W2img, gb0, gb1, gb2, gWf, gbf, out, logterm);
  reduce_kernel<<<kB, 256, 0, stream>>>(logterm, out + (size_t)kN * kD);
}

// Round 3
// 180.107 us; speedup vs baseline: 4.5086x; 1.3121x over previous
//
#include <hip/hip_runtime.h>
#include <math.h>

typedef _Float16 f16;
typedef _Float16 f16x4 __attribute__((ext_vector_type(4)));
typedef _Float16 f16x8 __attribute__((ext_vector_type(8)));
typedef float f32x16 __attribute__((ext_vector_type(16)));

#define MFMA_ __builtin_amdgcn_mfma_f32_32x32x16_f16
#define SLOPE_ 0.2f
constexpr int kB = 64, kT = 512, kD = 8, kH = 128, kE = 96;
constexpr int kL = 2;
constexpr int kFG = 145;            // H + L*D + 1
constexpr int kTM = 510;            // T - L
constexpr int kN = kB * kTM;        // 32640
constexpr int kK0 = 160;            // g L0 K padded (145 -> 160)

// LDS strides (f16 elems); dword stride mod 32 == 2 -> free 2-way banking
constexpr int SA  = 136;            // activations, K=128 (272 B row)
constexpr int S0  = 168;            // g A0, K=160      (336 B row)
constexpr int SE  = 104;            // fc emb A0, K=96  (208 B row)

// ================== weight pre-convert: f32 -> f16 images ===================
__global__ __launch_bounds__(256) void cvt_kernel(
    const float* __restrict__ gW0, const float* __restrict__ gW1,
    const float* __restrict__ gW2,
    const float* __restrict__ fcW0, const float* __restrict__ fcW1,
    const float* __restrict__ fcWf,
    f16* __restrict__ W0img, f16* __restrict__ W1img, f16* __restrict__ W2img,
    f16* __restrict__ fW0img, f16* __restrict__ fW1img, f16* __restrict__ fWfimg)
{
  const int stride = gridDim.x * 256;
  const int t0 = blockIdx.x*256 + threadIdx.x;
  for (int idx = t0; idx < kD*kH*kK0; idx += stride) {
    int dcol = idx / kK0, k = idx - dcol*kK0;
    W0img[idx] = (f16)(k < kFG ? gW0[dcol*kFG + k] : 0.f);
  }
  for (int idx = t0; idx < kD*kH*kH; idx += stride) {
    W1img[idx] = (f16)gW1[idx];
    W2img[idx] = (f16)gW2[idx];
  }
  for (int idx = t0; idx < kH*kE; idx += stride) fW0img[idx] = (f16)fcW0[idx];
  for (int idx = t0; idx < kH*kH; idx += stride) {
    fW1img[idx] = (f16)fcW1[idx];
    fWfimg[idx] = (f16)fcWf[idx];
  }
}

// =================== fc_mlp, fp16 MFMA: emb(N,96)->embh(N,128) f16 ==========
// Block: 256 thr = 4 waves, 64 rows. wave = coltile (32 cols), both rowhalves.
__global__ __launch_bounds__(256, 4) void fc_kernel(
    const float* __restrict__ emb,
    const f16* __restrict__ W0i, const float* __restrict__ b0,
    const f16* __restrict__ W1i, const float* __restrict__ b1,
    const f16* __restrict__ Wfi, const float* __restrict__ bf,
    f16* __restrict__ out)
{
  __shared__ char smem[17408];
  f16 (*A0)[SE]   = (f16(*)[SE])(smem);   // 64 x 104 (L0 input, aliased)
  f16 (*actH)[SA] = (f16(*)[SA])(smem);   // 64 x 136

  const int bn  = blockIdx.x * 64;
  const int tid = threadIdx.x;
  const int wave = tid >> 6, lane = tid & 63;
  const int l31 = lane & 31;
  const int lh8 = (lane >> 5) * 8;
  const int lr4 = (lane >> 5) * 4;
  const int c0  = wave * 32;
  const int mycol = c0 + l31;

  // prefetch L0 weight fragments (K=96 -> 6 frags)
  f16x8 w0f[6];
  #pragma unroll
  for (int kk = 0; kk < 6; ++kk)
    w0f[kk] = *(const f16x8*)(W0i + mycol*kE + kk*16 + lh8);
  const float fb0 = b0[mycol], fb1 = b1[mycol], fbf = bf[mycol];

  // stage emb tile (64 x 96) f32 -> f16
  #pragma unroll
  for (int i = 0; i < 6; ++i) {
    int idx = tid + i*256;              // 1536 float4s
    int r = idx / 24, c4 = idx % 24;
    float4 v = *(const float4*)(emb + (size_t)(bn + r)*kE + c4*4);
    f16x4 h; h[0] = (f16)v.x; h[1] = (f16)v.y; h[2] = (f16)v.z; h[3] = (f16)v.w;
    *(f16x4*)&A0[r][c4*4] = h;
  }
  __syncthreads();

  // prefetch L1 + Lf fragments (overlap with L0 compute)
  f16x8 w1f[8], wff[8];
  #pragma unroll
  for (int kk = 0; kk < 8; ++kk)
    w1f[kk] = *(const f16x8*)(W1i + mycol*kH + kk*16 + lh8);
  #pragma unroll
  for (int kk = 0; kk < 8; ++kk)
    wff[kk] = *(const f16x8*)(Wfi + mycol*kH + kk*16 + lh8);

  // L0 (K=96)
  f32x16 p0 = {}, p1 = {};
  #pragma unroll
  for (int kk = 0; kk < 6; ++kk) {
    f16x8 a0 = *(const f16x8*)&A0[l31][kk*16 + lh8];
    f16x8 a1 = *(const f16x8*)&A0[32 + l31][kk*16 + lh8];
    p0 = MFMA_(a0, w0f[kk], p0, 0, 0, 0);
    p1 = MFMA_(a1, w0f[kk], p1, 0, 0, 0);
  }
  __syncthreads();
  #pragma unroll
  for (int r = 0; r < 16; ++r) {
    int row = (r & 3) + ((r >> 2) * 8) + lr4;
    float z0 = p0[r] + fb0; actH[row][mycol]      = (f16)(z0 >= 0.f ? z0 : SLOPE_*z0);
    float z1 = p1[r] + fb0; actH[32 + row][mycol] = (f16)(z1 >= 0.f ? z1 : SLOPE_*z1);
  }
  __syncthreads();

  // L1 (K=128)
  f32x16 q0 = {}, q1 = {};
  #pragma unroll
  for (int kk = 0; kk < 8; ++kk) {
    f16x8 a0 = *(const f16x8*)&actH[l31][kk*16 + lh8];
    f16x8 a1 = *(const f16x8*)&actH[32 + l31][kk*16 + lh8];
    q0 = MFMA_(a0, w1f[kk], q0, 0, 0, 0);
    q1 = MFMA_(a1, w1f[kk], q1, 0, 0, 0);
  }
  __syncthreads();
  #pragma unroll
  for (int r = 0; r < 16; ++r) {
    int row = (r & 3) + ((r >> 2) * 8) + lr4;
    float z0 = q0[r] + fb1; actH[row][mycol]      = (f16)(z0 >= 0.f ? z0 : SLOPE_*z0);
    float z1 = q1[r] + fb1; actH[32 + row][mycol] = (f16)(z1 >= 0.f ? z1 : SLOPE_*z1);
  }
  __syncthreads();

  // Lf (K=128, no activation)
  f32x16 s0 = {}, s1 = {};
  #pragma unroll
  for (int kk = 0; kk < 8; ++kk) {
    f16x8 a0 = *(const f16x8*)&actH[l31][kk*16 + lh8];
    f16x8 a1 = *(const f16x8*)&actH[32 + l31][kk*16 + lh8];
    s0 = MFMA_(a0, wff[kk], s0, 0, 0, 0);
    s1 = MFMA_(a1, wff[kk], s1, 0, 0, 0);
  }
  __syncthreads();
  #pragma unroll
  for (int r = 0; r < 16; ++r) {
    int row = (r & 3) + ((r >> 2) * 8) + lr4;
    actH[row][mycol]      = (f16)(s0[r] + fbf);
    actH[32 + row][mycol] = (f16)(s1[r] + fbf);
  }
  __syncthreads();
  // vector store to global
  #pragma unroll
  for (int i = 0; i < 4; ++i) {
    int idx = tid + i*256;              // 1024 f16x8s
    int r = idx >> 4, c8 = idx & 15;
    *(f16x8*)(out + (size_t)(bn + r)*kH + c8*8) = *(const f16x8*)&actH[r][c8*8];
  }
}

// ==================== g_mlp fwd + JVP, fp16 MFMA ============================
// Block: 256 thr = 4 waves, one d, 64 rows. wave = coltile (32 cols), both
// rowhalves. Weights: global -> registers (prefetched), no LDS staging.
__global__ __launch_bounds__(256, 4) void g_kernel(
    const float* __restrict__ x, const f16* __restrict__ embh,
    const f16* __restrict__ W0img, const f16* __restrict__ W1img,
    const f16* __restrict__ W2img,
    const float* __restrict__ gb0, const float* __restrict__ gb1,
    const float* __restrict__ gb2, const float* __restrict__ gWf,
    const float* __restrict__ gbf,
    float* __restrict__ resid, float* __restrict__ logterm)
{
  __shared__ char smem[35328];
  f16 (*A0)[S0]   = (f16(*)[S0])(smem);            // 64 x 168 (L0, aliased)
  f16 (*actH)[SA] = (f16(*)[SA])(smem);            // 64 x 136
  f16 (*actT)[SA] = (f16(*)[SA])(smem + 17408);    // 64 x 136
  float* swf      = (float*)(smem + 34816);        // 128 f32

  const int d   = blockIdx.y;
  const int bn  = blockIdx.x * 64;
  const int tid = threadIdx.x;
  const int wave = tid >> 6, lane = tid & 63;
  const int l31 = lane & 31;
  const int lh8 = (lane >> 5) * 8;
  const int lr4 = (lane >> 5) * 4;
  const int c0  = wave * 32;
  const int mycol = c0 + l31;

  const f16* W0d = W0img + d*kH*kK0;
  const f16* W1d = W1img + d*kH*kH;
  const f16* W2d = W2img + d*kH*kH;

  // prefetch L0 weight fragments (K=160 -> 10 frags) + per-lane scalars
  f16x8 w0f[10];
  #pragma unroll
  for (int kk = 0; kk < 10; ++kk)
    w0f[kk] = *(const f16x8*)(W0d + mycol*kK0 + kk*16 + lh8);
  const float w144 = (float)W0d[mycol*kK0 + 144];
  const float bb0 = gb0[d*kH + mycol];
  const float bb1 = gb1[d*kH + mycol];
  const float bb2 = gb2[d*kH + mycol];

  if (tid < kH) swf[tid] = gWf[d*kH + tid];

  // stage A0 = [embh | yy | xx_d | 0pad], 64 x 160
  #pragma unroll
  for (int i = 0; i < 4; ++i) {
    int idx = tid + i*256; int r = idx >> 4, c8 = idx & 15;
    *(f16x8*)&A0[r][c8*8] = *(const f16x8*)(embh + (size_t)(bn + r)*kH + c8*8);
  }
  #pragma unroll
  for (int i = 0; i < 8; ++i) {
    int idx = tid + i*256; int r = idx >> 5, c = idx & 31;  // col = 128+c
    int n = bn + r, b = n / kTM, t = n - b*kTM;
    float v;
    if (c < 16)       v = x[(b*kT + t + (c >> 3))*kD + (c & 7)];
    else if (c == 16) v = x[(b*kT + t + kL)*kD + d];
    else              v = 0.f;
    A0[r][128 + c] = (f16)v;
  }
  __syncthreads();

  // prefetch W1 fragments (in flight during L0 compute)
  f16x8 w1f[8];
  #pragma unroll
  for (int kk = 0; kk < 8; ++kk)
    w1f[kk] = *(const f16x8*)(W1d + mycol*kH + kk*16 + lh8);

  // ---- L0 (K=160, primal only; tangent seed = w144*mask)
  f32x16 p0 = {}, p1 = {};
  #pragma unroll
  for (int kk = 0; kk < 10; ++kk) {
    f16x8 a0 = *(const f16x8*)&A0[l31][kk*16 + lh8];
    f16x8 a1 = *(const f16x8*)&A0[32 + l31][kk*16 + lh8];
    p0 = MFMA_(a0, w0f[kk], p0, 0, 0, 0);
    p1 = MFMA_(a1, w0f[kk], p1, 0, 0, 0);
  }
  __syncthreads();   // all A0 reads done before actH/actT overwrite
  #pragma unroll
  for (int r = 0; r < 16; ++r) {
    int row = (r & 3) + ((r >> 2) * 8) + lr4;
    float z0 = p0[r] + bb0; float m0 = z0 >= 0.f ? 1.f : SLOPE_;
    actH[row][mycol] = (f16)(z0*m0);
    actT[row][mycol] = (f16)(w144*m0);
    float z1 = p1[r] + bb0; float m1 = z1 >= 0.f ? 1.f : SLOPE_;
    actH[32 + row][mycol] = (f16)(z1*m1);
    actT[32 + row][mycol] = (f16)(w144*m1);
  }
  __syncthreads();

  // ---- L1 (K=128, primal + tangent share weight regs)
  f32x16 qa0 = {}, qa1 = {}, qt0 = {}, qt1 = {};
  #pragma unroll
  for (int kk = 0; kk < 8; ++kk) {
    int ko = kk*16 + lh8;
    f16x8 aP0 = *(const f16x8*)&actH[l31][ko];
    f16x8 aT0 = *(const f16x8*)&actT[l31][ko];
    f16x8 aP1 = *(const f16x8*)&actH[32 + l31][ko];
    f16x8 aT1 = *(const f16x8*)&actT[32 + l31][ko];
    qa0 = MFMA_(aP0, w1f[kk], qa0, 0, 0, 0);
    qt0 = MFMA_(aT0, w1f[kk], qt0, 0, 0, 0);
    qa1 = MFMA_(aP1, w1f[kk], qa1, 0, 0, 0);
    qt1 = MFMA_(aT1, w1f[kk], qt1, 0, 0, 0);
  }
  // prefetch W2 fragments (w1f dead; overlap with epilogue + barrier)
  f16x8 w2f[8];
  #pragma unroll
  for (int kk = 0; kk < 8; ++kk)
    w2f[kk] = *(const f16x8*)(W2d + mycol*kH + kk*16 + lh8);
  __syncthreads();
  #pragma unroll
  for (int r = 0; r < 16; ++r) {
    int row = (r & 3) + ((r >> 2) * 8) + lr4;
    float z0 = qa0[r] + bb1; float m0 = z0 >= 0.f ? 1.f : SLOPE_;
    actH[row][mycol] = (f16)(z0*m0);
    actT[row][mycol] = (f16)(qt0[r]*m0);
    float z1 = qa1[r] + bb1; float m1 = z1 >= 0.f ? 1.f : SLOPE_;
    actH[32 + row][mycol] = (f16)(z1*m1);
    actT[32 + row][mycol] = (f16)(qt1[r]*m1);
  }
  __syncthreads();

  // ---- L2
  f32x16 ra0 = {}, ra1 = {}, rt0 = {}, rt1 = {};
  #pragma unroll
  for (int kk = 0; kk < 8; ++kk) {
    int ko = kk*16 + lh8;
    f16x8 aP0 = *(const f16x8*)&actH[l31][ko];
    f16x8 aT0 = *(const f16x8*)&actT[l31][ko];
    f16x8 aP1 = *(const f16x8*)&actH[32 + l31][ko];
    f16x8 aT1 = *(const f16x8*)&actT[32 + l31][ko];
    ra0 = MFMA_(aP0, w2f[kk], ra0, 0, 0, 0);
    rt0 = MFMA_(aT0, w2f[kk], rt0, 0, 0, 0);
    ra1 = MFMA_(aP1, w2f[kk], ra1, 0, 0, 0);
    rt1 = MFMA_(aT1, w2f[kk], rt1, 0, 0, 0);
  }
  __syncthreads();
  #pragma unroll
  for (int r = 0; r < 16; ++r) {
    int row = (r & 3) + ((r >> 2) * 8) + lr4;
    float z0 = ra0[r] + bb2; float m0 = z0 >= 0.f ? 1.f : SLOPE_;
    actH[row][mycol] = (f16)(z0*m0);
    actT[row][mycol] = (f16)(rt0[r]*m0);
    float z1 = ra1[r] + bb2; float m1 = z1 >= 0.f ? 1.f : SLOPE_;
    actH[32 + row][mycol] = (f16)(z1*m1);
    actT[32 + row][mycol] = (f16)(rt1[r]*m1);
  }
  __syncthreads();

  // ---- final: p = H2.wf, tp = T2.wf (4 threads per row)
  {
    int r = tid >> 2, q = (tid & 3) * 32;
    float p = 0.f, tp = 0.f;
    #pragma unroll
    for (int j = 0; j < 32; j += 8) {
      f16x8 h8 = *(const f16x8*)&actH[r][q + j];
      f16x8 t8 = *(const f16x8*)&actT[r][q + j];
      #pragma unroll
      for (int e = 0; e < 8; ++e) {
        float w = swf[q + j + e];
        p  += (float)h8[e] * w;
        tp += (float)t8[e] * w;
      }
    }
    p  += __shfl_down(p, 2, 4);  p  += __shfl_down(p, 1, 4);
    tp += __shfl_down(tp, 2, 4); tp += __shfl_down(tp, 1, 4);
    if ((tid & 3) == 0) {
      int n = bn + r;
      resid[(size_t)n*kD + d]   = p + gbf[d];
      logterm[(size_t)n*kD + d] = logf(fabsf(tp));
    }
  }
}

// ---- per-batch sum of 510*8 log terms --------------------------------------
__global__ __launch_bounds__(256) void reduce_kernel(
    const float* __restrict__ lt, float* __restrict__ out)
{
  const int b = blockIdx.x;
  float s = 0.f;
  for (int i = threadIdx.x; i < kTM*kD; i += 256)
    s += lt[b*kTM*kD + i];
  #pragma unroll
  for (int off = 32; off > 0; off >>= 1) s += __shfl_down(s, off, 64);
  __shared__ float red[4];
  if ((threadIdx.x & 63) == 0) red[threadIdx.x >> 6] = s;
  __syncthreads();
  if (threadIdx.x == 0) out[b] = red[0] + red[1] + red[2] + red[3];
}

extern "C" void kernel_launch(void* const* d_in, const int* in_sizes, int n_in,
                              void* d_out, int out_size, void* d_ws, size_t ws_size,
                              hipStream_t stream) {
  const float* x    = (const float*)d_in[0];
  const float* emb  = (const float*)d_in[1];
  const float* fcW0 = (const float*)d_in[2];
  const float* fcb0 = (const float*)d_in[3];
  const float* fcW1 = (const float*)d_in[4];
  const float* fcb1 = (const float*)d_in[5];
  const float* fcWf = (const float*)d_in[6];
  const float* fcbf = (const float*)d_in[7];
  const float* gW0  = (const float*)d_in[8];
  const float* gb0  = (const float*)d_in[9];
  const float* gW1  = (const float*)d_in[10];
  const float* gb1  = (const float*)d_in[11];
  const float* gW2  = (const float*)d_in[12];
  const float* gb2  = (const float*)d_in[13];
  const float* gWf  = (const float*)d_in[14];
  const float* gbf  = (const float*)d_in[15];
  float* out = (float*)d_out;

  // workspace layout (all 16B-aligned)
  char* ws = (char*)d_ws;
  f16*   embh    = (f16*)ws;                          ws += (size_t)kN*kH*2;
  float* logterm = (float*)ws;                        ws += (size_t)kN*kD*4;
  f16*   W0img   = (f16*)ws;                          ws += (size_t)kD*kH*kK0*2;
  f16*   W1img   = (f16*)ws;                          ws += (size_t)kD*kH*kH*2;
  f16*   W2img   = (f16*)ws;                          ws += (size_t)kD*kH*kH*2;
  f16*   fW0img  = (f16*)ws;                          ws += (size_t)kH*kE*2;
  f16*   fW1img  = (f16*)ws;                          ws += (size_t)kH*kH*2;
  f16*   fWfimg  = (f16*)ws;

  cvt_kernel<<<256, 256, 0, stream>>>(gW0, gW1, gW2, fcW0, fcW1, fcWf,
                                      W0img, W1img, W2img,
                                      fW0img, fW1img, fWfimg);
  fc_kernel<<<kN / 64, 256, 0, stream>>>(emb, fW0img, fcb0, fW1img, fcb1,
                                         fWfimg, fcbf, embh);
  g_kernel<<<dim3(kN / 64, kD), 256, 0, stream>>>(
      x, embh, W0img, W1img, W2img, gb0, gb1, gb2, gWf, gbf, out, logterm);
  reduce_kernel<<<kB, 256, 0, stream>>>(logterm, out + (size_t)kN * kD);
}

// Round 4
// 176.579 us; speedup vs baseline: 4.5986x; 1.0200x over previous
//
#include <hip/hip_runtime.h>
#include <math.h>

typedef _Float16 f16;
typedef _Float16 f16x4 __attribute__((ext_vector_type(4)));
typedef _Float16 f16x8 __attribute__((ext_vector_type(8)));
typedef float f32x16 __attribute__((ext_vector_type(16)));

#define MFMA_ __builtin_amdgcn_mfma_f32_32x32x16_f16
#define SLOPE_ 0.2f

constexpr int kB = 64, kT = 512, kD = 8, kH = 128, kE = 96;
constexpr int kFG = 145, kTM = 510, kN = kB * kTM;   // N = 32640 = 255*128
constexpr int K0 = 144;                              // g W0 img K (emb 128 + yy 16)

// ---- stage NFB frag-blocks (64 lanes x 16 B, fragment-linear) into LDS -----
// Source W row-major [128 x SK] f16. frag fb=(c,t): lane l -> W[t*32+(l&31)][c*16+(l>>5)*8 ..+7]
template<int NFB>
__device__ __forceinline__ void stage_w(f16* buf, const f16* W, int SK,
                                        int wave, int lane) {
  constexpr int PER = NFB / 4;
  const int l31 = lane & 31, h5 = lane >> 5;
  f16x8 tmp[PER];
  #pragma unroll
  for (int i = 0; i < PER; ++i) {
    int fb = wave + i*4, c = fb >> 2, t = fb & 3;
    tmp[i] = *(const f16x8*)(W + (t*32 + l31)*SK + c*16 + h5*8);
  }
  #pragma unroll
  for (int i = 0; i < PER; ++i)
    *(f16x8*)(buf + (wave + i*4)*512 + lane*8) = tmp[i];
}

__device__ __forceinline__ f16x8 afrag(const f16* buf, int c, int t, int lane) {
  return *(const f16x8*)(buf + (c*4 + t)*512 + lane*8);
}

// ---- build next-layer B-fragment from held quads via lane^32 exchange ------
// hq[tile][quad]: quad q holds act[n=lane&31][h = 32t + 8q + 4*h5 + e]
__device__ __forceinline__ f16x8 xfrag(const f16x4 (&hq)[4][4], int c, int h5) {
  const int t = c >> 1, p2 = (c & 1) * 2;
  f16x4 kq = h5 ? hq[t][p2+1] : hq[t][p2];
  f16x4 sq = h5 ? hq[t][p2]   : hq[t][p2+1];
  union { f16x4 v; unsigned int u[2]; } s, r;
  s.v = sq;
  r.u[0] = __shfl_xor(s.u[0], 32, 64);
  r.u[1] = __shfl_xor(s.u[1], 32, 64);
  f16x4 lo = h5 ? r.v : kq;
  f16x4 hi = h5 ? kq : r.v;
  union { f16x8 v8; f16x4 h[2]; } o;
  o.h[0] = lo; o.h[1] = hi;
  return o.v8;
}

// ================== weight pre-convert: f32 -> f16 images ===================
__global__ __launch_bounds__(256) void cvt_kernel(
    const float* __restrict__ gW0, const float* __restrict__ gW1,
    const float* __restrict__ gW2,
    const float* __restrict__ fcW0, const float* __restrict__ fcW1,
    const float* __restrict__ fcWf,
    f16* __restrict__ W0img, f16* __restrict__ W1img, f16* __restrict__ W2img,
    f16* __restrict__ fW0img, f16* __restrict__ fW1img, f16* __restrict__ fWfimg)
{
  const int stride = gridDim.x * 256;
  const int t0 = blockIdx.x*256 + threadIdx.x;
  // g W0: image k 0..143 maps directly to source f 0..143 (xx/bias handled in-kernel)
  for (int idx = t0; idx < kD*kH*K0; idx += stride) {
    int dc = idx / K0, k = idx - dc*K0;
    W0img[idx] = (f16)gW0[dc*kFG + k];
  }
  for (int idx = t0; idx < kD*kH*kH; idx += stride) {
    W1img[idx] = (f16)gW1[idx];
    W2img[idx] = (f16)gW2[idx];
  }
  for (int idx = t0; idx < kH*kE; idx += stride) fW0img[idx] = (f16)fcW0[idx];
  for (int idx = t0; idx < kH*kH; idx += stride) {
    fW1img[idx] = (f16)fcW1[idx];
    fWfimg[idx] = (f16)fcWf[idx];
  }
}

// ============ fc_mlp: emb(N,96) -> embh(N,128) f16, no LDS act ==============
__global__ __launch_bounds__(256, 2) void fc_kernel(
    const float* __restrict__ emb,
    const f16* __restrict__ W0i, const float* __restrict__ b0,
    const f16* __restrict__ W1i, const float* __restrict__ b1,
    const f16* __restrict__ Wfi, const float* __restrict__ bf,
    f16* __restrict__ out)
{
  __shared__ f16 wbuf[32*512];
  __shared__ float lb0[kH], lb1[kH], lbf[kH];
  const int bn = blockIdx.x * 128;
  const int tid = threadIdx.x, wave = tid >> 6, lane = tid & 63;
  const int l31 = lane & 31, h5 = lane >> 5;
  const int n = bn + wave*32 + l31;

  if (tid < kH) { lb0[tid] = b0[tid]; lb1[tid] = b1[tid]; lbf[tid] = bf[tid]; }

  // B-frags from emb (f32 -> f16), chunks 0..5 (K=96)
  const float* erow = emb + (size_t)n*kE + h5*8;
  f16x8 embF[6];
  #pragma unroll
  for (int c = 0; c < 6; ++c) {
    float4 a = *(const float4*)(erow + c*16);
    float4 b = *(const float4*)(erow + c*16 + 4);
    f16x8 v;
    v[0]=(f16)a.x; v[1]=(f16)a.y; v[2]=(f16)a.z; v[3]=(f16)a.w;
    v[4]=(f16)b.x; v[5]=(f16)b.y; v[6]=(f16)b.z; v[7]=(f16)b.w;
    embF[c] = v;
  }
  stage_w<24>(wbuf, W0i, kE, wave, lane);
  __syncthreads();                                  // B1: W0 ready

  f32x16 zero = {};
  f32x16 acc[4] = {zero, zero, zero, zero};
  #pragma unroll
  for (int c = 0; c < 6; ++c)
    #pragma unroll
    for (int t = 0; t < 4; ++t)
      acc[t] = MFMA_(afrag(wbuf, c, t, lane), embF[c], acc[t], 0, 0, 0);
  __syncthreads();                                  // B2: W0 reads done
  stage_w<32>(wbuf, W1i, kH, wave, lane);

  f16x4 hP[4][4];
  #pragma unroll
  for (int t = 0; t < 4; ++t)
    #pragma unroll
    for (int q = 0; q < 4; ++q) {
      float4 b4 = *(const float4*)&lb0[t*32 + q*8 + h5*4];
      const float* bp = (const float*)&b4;
      f16x4 v;
      #pragma unroll
      for (int e = 0; e < 4; ++e) {
        float z = acc[t][q*4+e] + bp[e];
        v[e] = (f16)fmaxf(z, SLOPE_*z);
      }
      hP[t][q] = v;
    }
  __syncthreads();                                  // B3: W1 ready

  #pragma unroll
  for (int t = 0; t < 4; ++t) acc[t] = zero;
  #pragma unroll
  for (int c = 0; c < 8; ++c) {
    f16x8 bP = xfrag(hP, c, h5);
    #pragma unroll
    for (int t = 0; t < 4; ++t)
      acc[t] = MFMA_(afrag(wbuf, c, t, lane), bP, acc[t], 0, 0, 0);
  }
  __syncthreads();                                  // B4: W1 reads done
  stage_w<32>(wbuf, Wfi, kH, wave, lane);

  #pragma unroll
  for (int t = 0; t < 4; ++t)
    #pragma unroll
    for (int q = 0; q < 4; ++q) {
      float4 b4 = *(const float4*)&lb1[t*32 + q*8 + h5*4];
      const float* bp = (const float*)&b4;
      f16x4 v;
      #pragma unroll
      for (int e = 0; e < 4; ++e) {
        float z = acc[t][q*4+e] + bp[e];
        v[e] = (f16)fmaxf(z, SLOPE_*z);
      }
      hP[t][q] = v;
    }
  __syncthreads();                                  // B5: Wf ready

  f32x16 accf[4] = {zero, zero, zero, zero};
  #pragma unroll
  for (int c = 0; c < 8; ++c) {
    f16x8 bP = xfrag(hP, c, h5);
    #pragma unroll
    for (int t = 0; t < 4; ++t)
      accf[t] = MFMA_(afrag(wbuf, c, t, lane), bP, accf[t], 0, 0, 0);
  }
  // final epilogue (no lrelu) -> quads -> exchange -> row-major store
  #pragma unroll
  for (int t = 0; t < 4; ++t)
    #pragma unroll
    for (int q = 0; q < 4; ++q) {
      float4 b4 = *(const float4*)&lbf[t*32 + q*8 + h5*4];
      const float* bp = (const float*)&b4;
      f16x4 v;
      #pragma unroll
      for (int e = 0; e < 4; ++e) v[e] = (f16)(accf[t][q*4+e] + bp[e]);
      hP[t][q] = v;
    }
  #pragma unroll
  for (int c = 0; c < 8; ++c) {
    f16x8 v = xfrag(hP, c, h5);
    *(f16x8*)(out + (size_t)n*kH + c*16 + h5*8) = v;
  }
}

// ========== g_mlp fwd + JVP: register-chained layers, fused logdet ==========
__global__ __launch_bounds__(256, 2) void g_kernel(
    const float* __restrict__ x, const f16* __restrict__ embh,
    const f16* __restrict__ W0img, const f16* __restrict__ W1img,
    const f16* __restrict__ W2img,
    const float* __restrict__ gW0f32,
    const float* __restrict__ gb0, const float* __restrict__ gb1,
    const float* __restrict__ gb2, const float* __restrict__ gWf,
    const float* __restrict__ gbf,
    float* __restrict__ resid, float* __restrict__ logdet)
{
  __shared__ f16 wbuf[36*512];                     // 36 KB, reused per layer
  __shared__ float lwf[kH], lw144[kH], lb0[kH], lb1[kH], lb2[kH];
  __shared__ float part[8];

  const int d = blockIdx.y, bn = blockIdx.x * 128;
  const int tid = threadIdx.x, wave = tid >> 6, lane = tid & 63;
  const int l31 = lane & 31, h5 = lane >> 5;
  const int n = bn + wave*32 + l31;
  const int b = n / kTM, tt = n - b*kTM;

  if (tid < kH) {
    lwf[tid]   = gWf[d*kH + tid];
    lw144[tid] = gW0f32[(d*kH + tid)*kFG + 144];
    lb0[tid]   = gb0[d*kH + tid];
    lb1[tid]   = gb1[d*kH + tid];
    lb2[tid]   = gb2[d*kH + tid];
  }

  // B-frags: embh chunks 0..7 (already in B-layout), yy chunk 8, xx scalar
  const f16* erow = embh + (size_t)n*kH + h5*8;
  f16x8 embF[8];
  #pragma unroll
  for (int c = 0; c < 8; ++c) embF[c] = *(const f16x8*)(erow + c*16);
  const float* xp = x + ((size_t)b*kT + tt + h5)*kD;
  float4 xa = *(const float4*)xp;
  float4 xb = *(const float4*)(xp + 4);
  const float xxv = x[((size_t)b*kT + tt + 2)*kD + d];

  stage_w<36>(wbuf, W0img + d*kH*K0, K0, wave, lane);
  __syncthreads();                                  // B1: W0 ready

  f16x8 f8;
  f8[0]=(f16)xa.x; f8[1]=(f16)xa.y; f8[2]=(f16)xa.z; f8[3]=(f16)xa.w;
  f8[4]=(f16)xb.x; f8[5]=(f16)xb.y; f8[6]=(f16)xb.z; f8[7]=(f16)xb.w;

  f32x16 zero = {};
  f32x16 accP[4] = {zero, zero, zero, zero};
  f32x16 accT[4] = {zero, zero, zero, zero};

  // ---- L0 (primal only; tangent seed = w144*mask in epilogue)
  #pragma unroll
  for (int c = 0; c < 8; ++c)
    #pragma unroll
    for (int t = 0; t < 4; ++t)
      accP[t] = MFMA_(afrag(wbuf, c, t, lane), embF[c], accP[t], 0, 0, 0);
  #pragma unroll
  for (int t = 0; t < 4; ++t)
    accP[t] = MFMA_(afrag(wbuf, 8, t, lane), f8, accP[t], 0, 0, 0);
  __syncthreads();                                  // B2: W0 reads done
  stage_w<32>(wbuf, W1img + d*kH*kH, kH, wave, lane);

  f16x4 hP[4][4], hT[4][4];
  #pragma unroll
  for (int t = 0; t < 4; ++t)
    #pragma unroll
    for (int q = 0; q < 4; ++q) {
      float4 w4 = *(const float4*)&lw144[t*32 + q*8 + h5*4];
      float4 b4 = *(const float4*)&lb0[t*32 + q*8 + h5*4];
      const float* wp = (const float*)&w4;
      const float* bp = (const float*)&b4;
      f16x4 vp, vt;
      #pragma unroll
      for (int e = 0; e < 4; ++e) {
        float z = accP[t][q*4+e] + xxv*wp[e] + bp[e];
        vp[e] = (f16)fmaxf(z, SLOPE_*z);
        vt[e] = (f16)((z >= 0.f) ? wp[e] : SLOPE_*wp[e]);
      }
      hP[t][q] = vp; hT[t][q] = vt;
    }
  __syncthreads();                                  // B3: W1 ready

  // ---- L1 (primal + tangent share A-frags)
  #pragma unroll
  for (int t = 0; t < 4; ++t) { accP[t] = zero; accT[t] = zero; }
  #pragma unroll
  for (int c = 0; c < 8; ++c) {
    f16x8 bP = xfrag(hP, c, h5);
    f16x8 bT = xfrag(hT, c, h5);
    #pragma unroll
    for (int t = 0; t < 4; ++t) {
      f16x8 a = afrag(wbuf, c, t, lane);
      accP[t] = MFMA_(a, bP, accP[t], 0, 0, 0);
      accT[t] = MFMA_(a, bT, accT[t], 0, 0, 0);
    }
  }
  __syncthreads();                                  // B4: W1 reads done
  stage_w<32>(wbuf, W2img + d*kH*kH, kH, wave, lane);

  #pragma unroll
  for (int t = 0; t < 4; ++t)
    #pragma unroll
    for (int q = 0; q < 4; ++q) {
      float4 b4 = *(const float4*)&lb1[t*32 + q*8 + h5*4];
      const float* bp = (const float*)&b4;
      f16x4 vp, vt;
      #pragma unroll
      for (int e = 0; e < 4; ++e) {
        float z = accP[t][q*4+e] + bp[e];
        float tv = accT[t][q*4+e];
        vp[e] = (f16)fmaxf(z, SLOPE_*z);
        vt[e] = (f16)((z >= 0.f) ? tv : SLOPE_*tv);
      }
      hP[t][q] = vp; hT[t][q] = vt;
    }
  __syncthreads();                                  // B5: W2 ready

  // ---- L2
  #pragma unroll
  for (int t = 0; t < 4; ++t) { accP[t] = zero; accT[t] = zero; }
  #pragma unroll
  for (int c = 0; c < 8; ++c) {
    f16x8 bP = xfrag(hP, c, h5);
    f16x8 bT = xfrag(hT, c, h5);
    #pragma unroll
    for (int t = 0; t < 4; ++t) {
      f16x8 a = afrag(wbuf, c, t, lane);
      accP[t] = MFMA_(a, bP, accP[t], 0, 0, 0);
      accT[t] = MFMA_(a, bT, accT[t], 0, 0, 0);
    }
  }

  // ---- final epilogue + dot with wf (f32, no extra cvt)
  float p = 0.f, tp = 0.f;
  #pragma unroll
  for (int t = 0; t < 4; ++t)
    #pragma unroll
    for (int q = 0; q < 4; ++q) {
      float4 b4 = *(const float4*)&lb2[t*32 + q*8 + h5*4];
      float4 w4 = *(const float4*)&lwf[t*32 + q*8 + h5*4];
      const float* bp = (const float*)&b4;
      const float* wp = (const float*)&w4;
      #pragma unroll
      for (int e = 0; e < 4; ++e) {
        float z = accP[t][q*4+e] + bp[e];
        float tv = accT[t][q*4+e];
        float zl = fmaxf(z, SLOPE_*z);
        float tl = (z >= 0.f) ? tv : SLOPE_*tv;
        p  = fmaf(zl, wp[e], p);
        tp = fmaf(tl, wp[e], tp);
      }
    }
  p  += __shfl_xor(p, 32, 64);
  tp += __shfl_xor(tp, 32, 64);

  float llog = 0.f;
  if (!h5) {
    resid[(size_t)n*kD + d] = p + gbf[d];
    llog = logf(fabsf(tp));
  }
  // block partial of logdet, segmented over the (at most 2) batches it spans
  const int bfirst = bn / kTM;
  float s0 = (b == bfirst) ? llog : 0.f;
  float s1 = llog - s0;
  #pragma unroll
  for (int off = 32; off > 0; off >>= 1) {
    s0 += __shfl_down(s0, off, 64);
    s1 += __shfl_down(s1, off, 64);
  }
  if (lane == 0) { part[wave*2] = s0; part[wave*2 + 1] = s1; }
  __syncthreads();                                  // B6
  if (tid == 0) {
    float S0 = part[0] + part[2] + part[4] + part[6];
    float S1 = part[1] + part[3] + part[5] + part[7];
    atomicAdd(&logdet[bfirst], S0);
    if (S1 != 0.f) atomicAdd(&logdet[bfirst + 1], S1);
  }
}

extern "C" void kernel_launch(void* const* d_in, const int* in_sizes, int n_in,
                              void* d_out, int out_size, void* d_ws, size_t ws_size,
                              hipStream_t stream) {
  const float* x    = (const float*)d_in[0];
  const float* emb  = (const float*)d_in[1];
  const float* fcW0 = (const float*)d_in[2];
  const float* fcb0 = (const float*)d_in[3];
  const float* fcW1 = (const float*)d_in[4];
  const float* fcb1 = (const float*)d_in[5];
  const float* fcWf = (const float*)d_in[6];
  const float* fcbf = (const float*)d_in[7];
  const float* gW0  = (const float*)d_in[8];
  const float* gb0  = (const float*)d_in[9];
  const float* gW1  = (const float*)d_in[10];
  const float* gb1  = (const float*)d_in[11];
  const float* gW2  = (const float*)d_in[12];
  const float* gb2  = (const float*)d_in[13];
  const float* gWf  = (const float*)d_in[14];
  const float* gbf  = (const float*)d_in[15];
  float* out = (float*)d_out;
  float* logdet = out + (size_t)kN * kD;

  char* ws = (char*)d_ws;
  f16* embh   = (f16*)ws;   ws += (size_t)kN*kH*2;
  f16* W0img  = (f16*)ws;   ws += (size_t)kD*kH*K0*2;
  f16* W1img  = (f16*)ws;   ws += (size_t)kD*kH*kH*2;
  f16* W2img  = (f16*)ws;   ws += (size_t)kD*kH*kH*2;
  f16* fW0img = (f16*)ws;   ws += (size_t)kH*kE*2;
  f16* fW1img = (f16*)ws;   ws += (size_t)kH*kH*2;
  f16* fWfimg = (f16*)ws;

  cvt_kernel<<<256, 256, 0, stream>>>(gW0, gW1, gW2, fcW0, fcW1, fcWf,
                                      W0img, W1img, W2img,
                                      fW0img, fW1img, fWfimg);
  fc_kernel<<<kN/128, 256, 0, stream>>>(emb, fW0img, fcb0, fW1img, fcb1,
                                        fWfimg, fcbf, embh);
  hipMemsetAsync((void*)logdet, 0, kB*sizeof(float), stream);
  g_kernel<<<dim3(kN/128, kD), 256, 0, stream>>>(
      x, embh, W0img, W1img, W2img, gW0, gb0, gb1, gb2, gWf, gbf,
      out, logdet);
}